// Round 7
// baseline (92.405 us; speedup 1.0000x reference)
//
#include <hip/hip_runtime.h>

#define N_KPS 1024
#define N_PTS 120000
#define BLOCK 512                  // 8 waves per block
#define KSPLIT 8                   // one wave per ctrl chunk
#define KCHUNK (N_KPS / KSPLIT)    // 128 ctrl points per wave = 2 reg-blocks
#define PTS_PER_BLOCK 128          // 64 lanes x 2 pts/lane

// r6 (s_load bcast): kernel ~34us. r7 (2x work/chunk): FLAT -> cost is
// per-eval, not per-chunk stall. r8 (poly): +26cyc/eval = added VALU at face
// value. r10 (LDS bcast): 41us, WORSE. Unified model: per-eval = 12cyc VALU
// + ~30cyc ctrl-DELIVERY idle, present for BOTH scalar-mem and LDS delivery
// (latency-bound uniform pipes, per-iter waitcnt). r11 (this round): deliver
// ctrl via REGISTERS. Each lane vector-loads ONE ctrl pt per 64-block
// (coalesced float2, prefetchable, 2 blocks loaded up front); hot loop
// broadcasts lane->SGPR via v_readlane_b32 with compile-time lane index
// (unrolled 64x). Zero hot-loop memory, no lgkmcnt. 18 instr per ctrl per
// 2 evals = 18cyc/eval. I$ ~18KB. All VALU ops read <=1 SGPR (ISA ok).
// DISCRIMINATOR: kernel ~14-18us (dur ->58-63) => delivery was the wall;
// flat ~30-34 => v_log_f32 trans throughput (~43cyc) is the wall -> hybrid
// poly/log split next. Predict VALUBusy>=60%, bank-conflict 0, VGPR ~40.
static __device__ __forceinline__ float rdlane(float v, int l) {
    return __builtin_bit_cast(
        float, __builtin_amdgcn_readlane(__builtin_bit_cast(int, v), l));
}

__global__ __launch_bounds__(BLOCK) void tps_warp_kernel(
    const float2* __restrict__ pts,
    const float*  __restrict__ kps,
    const float*  __restrict__ W,
    float2*       __restrict__ out)
{
    __shared__ float4 part[KSPLIT][64];    // 8KB partials

    const int tid = threadIdx.x;
    const int lane = tid & 63;
    const int wv = __builtin_amdgcn_readfirstlane(tid) >> 6;

    const int base = blockIdx.x * PTS_PER_BLOCK;
    const int j0 = base + lane;
    const int j1 = base + 64 + lane;
    const int j0c = j0 < N_PTS ? j0 : N_PTS - 1;
    const int j1c = j1 < N_PTS ? j1 : N_PTS - 1;
    const float2 p0 = pts[j0c];
    const float2 p1 = pts[j1c];

    // Each lane owns ctrl point (cb + lane) of block 0 and (cb + 64 + lane)
    // of block 1. Coalesced float2 loads, all issued up front; latency hides
    // under pts loads + block-0 compute.
    const float2* __restrict__ kp2 = (const float2*)kps;
    const float2* __restrict__ wp2 = (const float2*)W;
    const int cb = wv * KCHUNK;
    const float2 k0 = kp2[cb + lane];
    const float2 w0 = wp2[cb + lane];
    const float2 k1 = kp2[cb + 64 + lane];
    const float2 w1 = wp2[cb + 64 + lane];

    float ax0 = 0.f, ay0 = 0.f, ax1 = 0.f, ay1 = 0.f;

    // Per ctrl point: 4 readlane (VGPR->SGPR broadcast, compile-time lane
    // index) + 2x{sub,sub,fma,fma,mul,fma,fma} VALU + 2 logs (trans pipe).
    // Math identical to verified r6: fma-folded 1e-37 keeps log arg
    // positive/normal; d2==0 -> ~0 contribution (= reference where(l2==0,1)).
    auto block = [&](float2 kk, float2 ww) {
        #pragma unroll
        for (int c = 0; c < 64; ++c) {
            const float kx = rdlane(kk.x, c);
            const float ky = rdlane(kk.y, c);
            const float wx = rdlane(ww.x, c);
            const float wy = rdlane(ww.y, c);
            {
                float dx = kx - p0.x, dy = ky - p0.y;
                float d2 = fmaf(dy, dy, fmaf(dx, dx, 1e-37f));
                float v = d2 * __log2f(d2);
                ax0 = fmaf(v, wx, ax0);
                ay0 = fmaf(v, wy, ay0);
            }
            {
                float dx = kx - p1.x, dy = ky - p1.y;
                float d2 = fmaf(dy, dy, fmaf(dx, dx, 1e-37f));
                float v = d2 * __log2f(d2);
                ax1 = fmaf(v, wx, ax1);
                ay1 = fmaf(v, wy, ay1);
            }
        }
    };
    block(k0, w0);
    block(k1, w1);

    part[wv][lane] = make_float4(ax0, ay0, ax1, ay1);
    __syncthreads();

    // Verified r6 tail: wave 0 finalizes j0 (.x/.y), wave 1 finalizes j1
    // (.z/.w). Wave-uniform select, compile-time indices only.
    if (wv < 2) {
        const bool hi = (wv == 1);
        const float2 p = hi ? p1 : p0;
        const int j = hi ? j1 : j0;

        float sx = 0.f, sy = 0.f;
        #pragma unroll
        for (int w = 0; w < KSPLIT; ++w) {
            float4 a = part[w][lane];
            sx += hi ? a.z : a.x;
            sy += hi ? a.w : a.y;
        }

        const float scale = 0.34657359027997264f;  // 0.5 * ln(2)
        float w1x = W[2048], w1y = W[2049];
        float wxx = W[2050], wxy = W[2051];
        float wyx = W[2052], wyy = W[2053];

        if (j < N_PTS) {
            float ox = p.x + fmaf(scale, sx, fmaf(wxx, p.x, fmaf(wyx, p.y, w1x)));
            float oy = p.y + fmaf(scale, sy, fmaf(wxy, p.x, fmaf(wyy, p.y, w1y)));
            out[j] = make_float2(ox, oy);
        }
    }
}

extern "C" void kernel_launch(void* const* d_in, const int* in_sizes, int n_in,
                              void* d_out, int out_size, void* d_ws, size_t ws_size,
                              hipStream_t stream) {
    const float* pts = (const float*)d_in[0];   // [120000, 2]
    const float* kps = (const float*)d_in[1];   // [1024, 2]
    const float* W   = (const float*)d_in[2];   // [1027, 2]
    float* out = (float*)d_out;                 // [120000, 2]

    const int grid = (N_PTS + PTS_PER_BLOCK - 1) / PTS_PER_BLOCK;  // 938
    tps_warp_kernel<<<grid, BLOCK, 0, stream>>>(
        (const float2*)pts, kps, W, (float2*)out);
}

// Round 10
// 78.495 us; speedup vs baseline: 1.1772x; 1.1772x over previous
//
#include <hip/hip_runtime.h>

#define N_KPS 1024
#define N_PTS 120000
#define BLOCK 512                  // 8 waves per block
#define KSPLIT 8                   // one wave per K-chunk
#define KCHUNK (N_KPS / KSPLIT)    // 128 control points per wave
#define PTS_PER_BLOCK 128          // 64 lanes x 2 points/thread
#define CHUNK 8                    // ctrl points per pipelined chunk
#define NCHUNK (KCHUNK / CHUNK)    // 16

typedef float v2f __attribute__((ext_vector_type(2)));

// Ladder: s_load 34us kernel (r6, VERIFIED dur 78.3) | LDS 41 (r10) |
// readlane 41 (r11) | pk-asm: corrupt 3x incl. self-test-passing r13 ->
// ABANDONED (context-dependent, no disasm available in-loop).
// Model fit (r6/r7/r11, kernel = dur - 44.4us overhead):
//   T_slot = 2cyc*VALU_instr + T_log*N_log fits ALL configs at T_log ~= 30
//   issue-cyc per wave64 __log2f, idle ~1.0 => r6 IS the additive-issue
//   floor; logs are 69% of issue, VALU only 31% (pk would've bought 16%).
// r14 (this round): theory = __log2f lowers with a denormal-input guard
// (cmp + prescale + v_log_f32 + fixup ~= 30cyc); our arg is provably normal
// (>= 1e-37 via fma-folded epsilon), so use RAW v_log_f32 via
// __builtin_amdgcn_logf (log2 semantics, ~1ulp for normals). Single-variable
// change vs verified r6.
// Predict: T_log 30 -> 10-16 => kernel 34 -> 19-24us, dur 78.3 -> 63-68,
// absmax ~1.8 unchanged. Flat => T_log is genuine trans throughput and r6
// is within ~5% of the issue roofline.
#if __has_builtin(__builtin_amdgcn_logf)
#define FAST_LOG2(x) __builtin_amdgcn_logf(x)
#elif __has_builtin(__builtin_amdgcn_log_f32)
#define FAST_LOG2(x) __builtin_amdgcn_log_f32(x)
#else
#define FAST_LOG2(x) __log2f(x)
#endif

__global__ __launch_bounds__(BLOCK) void tps_warp_kernel(
    const float2* __restrict__ pts,
    const float*  __restrict__ kps,
    const float*  __restrict__ W,
    float2*       __restrict__ out)
{
    __shared__ float4 part[KSPLIT][64];

    const int lane = threadIdx.x & 63;
    // Provably wave-uniform wave id -> SGPR -> scalar loads for kps/W.
    const int wv = __builtin_amdgcn_readfirstlane(threadIdx.x) >> 6;

    const int base = blockIdx.x * PTS_PER_BLOCK;
    const int j0 = base + lane;
    const int j1 = base + 64 + lane;
    const int j0c = j0 < N_PTS ? j0 : N_PTS - 1;
    const int j1c = j1 < N_PTS ? j1 : N_PTS - 1;
    const float2 p0 = pts[j0c];
    const float2 p1 = pts[j1c];

    v2f px = {p0.x, p1.x};
    v2f py = {p0.y, p1.y};
    v2f zx = {0.0f, 0.0f};
    v2f zy = {0.0f, 0.0f};
    const v2f tiny = {1e-37f, 1e-37f};

    auto eval = [&](float kx, float ky, float wx, float wy) {
        v2f dx = v2f{kx, kx} - px;
        v2f dy = v2f{ky, ky} - py;
        // Epsilon folded into the chain: d2 >= 1e-37 (positive, NORMAL) ->
        // raw v_log_f32 is exact-enough, no denormal guard needed. d2==0
        // case gives 1e-37*log2(1e-37) ~ -1e-35 ~ 0, matching reference
        // where(l2==0,1) -> 0.5*1*ln(1) = 0.
        v2f d2 = __builtin_elementwise_fma(
            dy, dy, __builtin_elementwise_fma(dx, dx, tiny));
        v2f t;
        t.x = FAST_LOG2(d2.x);
        t.y = FAST_LOG2(d2.y);
        v2f v = d2 * t;                      // 0.5*ln2 folded in at the end
        zx = __builtin_elementwise_fma(v, v2f{wx, wx}, zx);
        zy = __builtin_elementwise_fma(v, v2f{wy, wy}, zy);
    };

    // Control data as float4 pairs: kp4[t] = {kx,ky,kx',ky'}, wp4[t] = {wx,wy,wx',wy'}.
    const float4* __restrict__ kp4 = (const float4*)kps;   // 512 entries
    const float4* __restrict__ wp4 = (const float4*)W;
    const int cbase = wv * (KCHUNK / 2);                   // float4 index base

    // Fully unrolled: prefetch copies become SSA renames; s_loads schedule
    // ahead under compiler control.
    #pragma unroll
    for (int c = 0; c < NCHUNK; ++c) {
        float4 kc[4], wc[4];
        #pragma unroll
        for (int t = 0; t < 4; ++t) {
            kc[t] = kp4[cbase + c * 4 + t];
            wc[t] = wp4[cbase + c * 4 + t];
        }
        #pragma unroll
        for (int t = 0; t < 4; ++t) {
            eval(kc[t].x, kc[t].y, wc[t].x, wc[t].y);
            eval(kc[t].z, kc[t].w, wc[t].z, wc[t].w);
        }
    }

    part[wv][lane] = make_float4(zx.x, zy.x, zx.y, zy.y);
    __syncthreads();

    // Verified r6 tail: wave 0 finalizes j0 (.x/.y), wave 1 finalizes j1
    // (.z/.w). Wave-uniform select, compile-time indices only.
    if (wv < 2) {
        const bool hi = (wv == 1);
        const float2 p = hi ? p1 : p0;
        const int j = hi ? j1 : j0;

        float sx = 0.f, sy = 0.f;
        #pragma unroll
        for (int w = 0; w < KSPLIT; ++w) {
            float4 a = part[w][lane];
            sx += hi ? a.z : a.x;
            sy += hi ? a.w : a.y;
        }

        const float scale = 0.34657359027997264f;  // 0.5 * ln(2)
        float w1x = W[2048], w1y = W[2049];
        float wxx = W[2050], wxy = W[2051];
        float wyx = W[2052], wyy = W[2053];

        if (j < N_PTS) {
            float ox = p.x + fmaf(scale, sx, fmaf(wxx, p.x, fmaf(wyx, p.y, w1x)));
            float oy = p.y + fmaf(scale, sy, fmaf(wxy, p.x, fmaf(wyy, p.y, w1y)));
            out[j] = make_float2(ox, oy);
        }
    }
}

extern "C" void kernel_launch(void* const* d_in, const int* in_sizes, int n_in,
                              void* d_out, int out_size, void* d_ws, size_t ws_size,
                              hipStream_t stream) {
    const float* pts = (const float*)d_in[0];   // [120000, 2]
    const float* kps = (const float*)d_in[1];   // [1024, 2]
    const float* W   = (const float*)d_in[2];   // [1027, 2]
    float* out = (float*)d_out;                 // [120000, 2]

    const int grid = (N_PTS + PTS_PER_BLOCK - 1) / PTS_PER_BLOCK;  // 938
    tps_warp_kernel<<<grid, BLOCK, 0, stream>>>(
        (const float2*)pts, kps, W, (float2*)out);
}